// Round 7
// baseline (3316.780 us; speedup 1.0000x reference)
//
#include <hip/hip_runtime.h>
#include <hip/hip_fp16.h>
#include <hip/hip_cooperative_groups.h>

typedef _Float16 f16;
typedef _Float16 half8 __attribute__((ext_vector_type(8)));
typedef _Float16 f16x4 __attribute__((ext_vector_type(4)));
typedef float floatx4 __attribute__((ext_vector_type(4)));
typedef unsigned long long u64;

#define BATCH 64
#define SEQ 512
#define EMB 512
#define HID 1024
#define GWG 8  // workgroups per group (512 threads each)

// ws layout (bytes):
//   [0, 262144)        abuf: 4 groups x 2 chains x 2 parity x 8192 f16
//                      (chain = independent 8-batch recurrence)
//   [262144, 2359296)  W16: W_aa as f16, 1M elements
//   [2359296, +2048)   counters: 8 x u32 (grp*2+chain) at 256B stride
// Protocol per chain = R0-proven: producer WG, after vmcnt(0)+syncthreads,
// atomicAdd(cnt_chain). Consumer at step s polls cnt_chain >= 8*s (tid0).
// Chains A,B interleaved per step in identical program order on all WGs:
// A's exchange latency hides under B's compute phase and vice versa.
#define ABUF_HALFS 131072
#define BAR_OFF 2359296

// ---------------- K0: convert W_aa fp32->f16; zero parity-0 planes + cnts ----
__global__ __launch_bounds__(256) void k0_cvt_waa(const float* __restrict__ W,
                                                  f16* __restrict__ W16,
                                                  f16* __restrict__ abuf,
                                                  unsigned* __restrict__ bar) {
    int gtid = blockIdx.x * 256 + threadIdx.x;  // 0..262143
    int i = gtid * 4;
    float4 v = *(const float4*)(W + i);
    f16x4 h;
    h[0] = (f16)v.x; h[1] = (f16)v.y; h[2] = (f16)v.z; h[3] = (f16)v.w;
    *(f16x4*)(W16 + i) = h;
    // zero parity-0 of each (group,chain) plane: plane pid=0..7 dwords
    // [pid*8192, pid*8192+4096)
    if (gtid < 32768) {
        int pid = gtid >> 12, off = gtid & 4095;
        ((unsigned*)abuf)[pid * 8192 + off] = 0u;
    }
    if (gtid < 8) bar[gtid * 64] = 0u;
}

// ---------------- K1: xproj = X @ W_ax^T + b_a -> d_out[s][b][h] -------------
// fp16 split-2 on X, single f16 W_ax. 64x64 tile, 4 waves 2x2. (validated R1)
__global__ __launch_bounds__(256) void k1_xproj(const float* __restrict__ X,
                                                const float* __restrict__ Wax,
                                                const float* __restrict__ ba,
                                                float* __restrict__ out) {
    __shared__ __align__(16) f16 Xhi[64][40];
    __shared__ __align__(16) f16 Xlo[64][40];
    __shared__ __align__(16) f16 Wh[64][40];
    const int tid  = threadIdx.x;
    const int lane = tid & 63;
    const int wave = tid >> 6;
    const int vm = wave >> 1, vn = wave & 1;
    const int m0 = blockIdx.x * 64;   // m = b*512 + s
    const int n0 = blockIdx.y * 64;   // n = h
    const int q = lane >> 4, c = lane & 15;
    const int srow = tid >> 2, scol = (tid & 3) * 8;

    floatx4 acc[2][2] = {};

    for (int kc = 0; kc < EMB; kc += 32) {
        const float* xp = X + (size_t)(m0 + srow) * EMB + kc + scol;
        float4 x0 = *(const float4*)xp;
        float4 x1 = *(const float4*)(xp + 4);
        float xv[8] = {x0.x, x0.y, x0.z, x0.w, x1.x, x1.y, x1.z, x1.w};
        half8 xh, xl;
#pragma unroll
        for (int j = 0; j < 8; j++) {
            f16 h = (f16)xv[j];
            xh[j] = h;
            xl[j] = (f16)(xv[j] - (float)h);
        }
        *(half8*)&Xhi[srow][scol] = xh;
        *(half8*)&Xlo[srow][scol] = xl;
        const float* wp = Wax + (size_t)(n0 + srow) * EMB + kc + scol;
        float4 w0 = *(const float4*)wp;
        float4 w1 = *(const float4*)(wp + 4);
        float wv[8] = {w0.x, w0.y, w0.z, w0.w, w1.x, w1.y, w1.z, w1.w};
        half8 wh8;
#pragma unroll
        for (int j = 0; j < 8; j++) wh8[j] = (f16)wv[j];
        *(half8*)&Wh[srow][scol] = wh8;
        __syncthreads();

#pragma unroll
        for (int im = 0; im < 2; im++) {
            half8 ahi = *(const half8*)&Xhi[vm * 32 + im * 16 + c][q * 8];
            half8 alo = *(const half8*)&Xlo[vm * 32 + im * 16 + c][q * 8];
#pragma unroll
            for (int in = 0; in < 2; in++) {
                half8 bf = *(const half8*)&Wh[vn * 32 + in * 16 + c][q * 8];
                acc[im][in] = __builtin_amdgcn_mfma_f32_16x16x32_f16(ahi, bf, acc[im][in], 0, 0, 0);
                acc[im][in] = __builtin_amdgcn_mfma_f32_16x16x32_f16(alo, bf, acc[im][in], 0, 0, 0);
            }
        }
        __syncthreads();
    }
#pragma unroll
    for (int im = 0; im < 2; im++) {
#pragma unroll
        for (int in = 0; in < 2; in++) {
            int n = n0 + vn * 32 + in * 16 + c;
            float bias = ba[n];
#pragma unroll
            for (int r = 0; r < 4; r++) {
                int m = m0 + vm * 32 + im * 16 + q * 4 + r;
                int b = m >> 9, s = m & 511;
                out[(size_t)(s * BATCH + b) * HID + n] = acc[im][in][r] + bias;
            }
        }
    }
}

// ---------------- K2: scan, two interleaved 8-batch chains per group ---------
// 32 WGs x 512 thr. group = blockIdx/8 (16 batches = chains A,B of 8),
// wig = (blockIdx%8)*8+wave, j0 = wig*16. W_aa rows in registers, shared by
// both chains. S rows 0..7 = chain A state, rows 8..15 = chain B; lanes c<8
// produce chain-A outputs, c>=8 chain-B (b = b0+c in both). Stale rows feed
// only discarded MFMA columns.
__global__ __launch_bounds__(512, 1) void k2_scan(const f16* __restrict__ W16,
                                                  float* __restrict__ out,
                                                  f16* __restrict__ abuf,
                                                  unsigned* __restrict__ bar) {
    __shared__ __align__(16) f16 S[16][1032];  // +8 pad
    const int tid  = threadIdx.x;
    const int lane = tid & 63;
    const int wave = tid >> 6;                        // 0..7
    const int grp  = blockIdx.x >> 3;                 // 0..3
    const int wig  = ((blockIdx.x & 7) << 3) + wave;  // 0..63
    const int j0   = wig << 4;
    const int b0   = grp << 4;
    const int q = lane >> 4, c = lane & 15;
    const int myChain = c >> 3;   // which chain this lane's outputs belong to
    const int cc = c & 7;         // batch-within-chain
    const int b = b0 + c;         // global batch (valid for the active chain)

    // A-operand (W) fragments resident for the whole scan (shared by chains):
    // lane holds W[j0+c][t*32 + q*8 .. +7] for t=0..31
    half8 w[32];
    {
        const f16* Wrow = W16 + (size_t)(j0 + c) * HID + q * 8;
#pragma unroll
        for (int t = 0; t < 32; t++) w[t] = *(const half8*)(Wrow + t * 32);
    }
    unsigned* const cnt0 = bar + (grp * 2 + 0) * 64;
    unsigned* const cnt1 = bar + (grp * 2 + 1) * 64;
    f16* const plane0 = abuf + (size_t)(grp * 2 + 0) * 16384;  // 2 parity x 8192
    f16* const plane1 = abuf + (size_t)(grp * 2 + 1) * 16384;

    for (int s = 0; s < SEQ; s++) {
#pragma unroll
        for (int h = 0; h < 2; h++) {
            unsigned* const cnt = h ? cnt1 : cnt0;
            f16* const plane   = h ? plane1 : plane0;
            const f16* src = plane + ((s & 1) ? 8192 : 0);
            f16* dst       = plane + ((s & 1) ? 0 : 8192);
            const bool act = (myChain == h);
            const size_t obase = ((size_t)s * BATCH + b) * HID + j0 + (q << 2);
            // xp prefetch (masked to active lanes; hides under poll+stage)
            float4 xp;
            if (act) xp = *(const float4*)(out + obase);
            // ---- wait: chain state ready when cnt >= 8*s (published one
            //      half-iteration ago -> usually no spin) ----
            if (tid == 0) {
                const unsigned tgt = (unsigned)(GWG * s);
                while (__hip_atomic_load(cnt, __ATOMIC_RELAXED,
                                         __HIP_MEMORY_SCOPE_AGENT) < tgt) {}
            }
            __syncthreads();  // B1
            // ---- stage 8 KB chain state: batch loads, then write LDS ----
            {
                u64 tmp[4];
#pragma unroll
                for (int it = 0; it < 4; it++)
                    tmp[it] = __hip_atomic_load((const u64*)(src + (it * 512 + tid) * 4),
                                                __ATOMIC_RELAXED, __HIP_MEMORY_SCOPE_AGENT);
#pragma unroll
                for (int it = 0; it < 4; it++) {
                    int idx = (it * 512 + tid) * 4;  // 0..8191 halves
                    *(u64*)&S[(h << 3) + (idx >> 10)][idx & 1023] = tmp[it];
                }
            }
            __syncthreads();  // B2
            // ---- K-loop: 32 chunks; rows of the other chain feed discarded
            //      output columns only ----
            floatx4 acc = {0.f, 0.f, 0.f, 0.f};
#pragma unroll
            for (int t = 0; t < 32; t++) {
                half8 bfrag = *(const half8*)&S[c][t * 32 + q * 8];
                acc = __builtin_amdgcn_mfma_f32_16x16x32_f16(w[t], bfrag, acc, 0, 0, 0);
            }
            // ---- epilogue (active half of lanes): j = j0+q*4+r, b = b0+c ----
            float4 v;
            if (act) {
                v.x = tanhf(xp.x + acc[0]);
                v.y = tanhf(xp.y + acc[1]);
                v.z = tanhf(xp.z + acc[2]);
                v.w = tanhf(xp.w + acc[3]);
                union { f16x4 h4; u64 u; } cv;
                cv.h4[0] = (f16)v.x; cv.h4[1] = (f16)v.y;
                cv.h4[2] = (f16)v.z; cv.h4[3] = (f16)v.w;
                __hip_atomic_store((u64*)(dst + cc * 1024 + j0 + (q << 2)), cv.u,
                                   __ATOMIC_RELAXED, __HIP_MEMORY_SCOPE_AGENT);
            }
            // ---- arrive: drain state stores, WG rendezvous, count up ----
            asm volatile("s_waitcnt vmcnt(0)" ::: "memory");
            __syncthreads();  // B3
            if (tid == 0)
                __hip_atomic_fetch_add(cnt, 1u, __ATOMIC_RELAXED, __HIP_MEMORY_SCOPE_AGENT);
            // ---- off the critical path: out + final-hidden stores ----
            if (act) {
                *(float4*)(out + obase) = v;
                if (s == SEQ - 1)
                    *(float4*)(out + (size_t)SEQ * BATCH * HID + (size_t)b * HID + j0 + (q << 2)) = v;
            }
        }
    }
}

extern "C" void kernel_launch(void* const* d_in, const int* in_sizes, int n_in,
                              void* d_out, int out_size, void* d_ws, size_t ws_size,
                              hipStream_t stream) {
    const float* X   = (const float*)d_in[0];
    const float* Wax = (const float*)d_in[1];
    const float* Waa = (const float*)d_in[2];
    const float* ba  = (const float*)d_in[3];
    float* out = (float*)d_out;

    f16* abuf = (f16*)d_ws;
    f16* W16  = abuf + ABUF_HALFS;
    unsigned* bar = (unsigned*)((char*)d_ws + BAR_OFF);

    k0_cvt_waa<<<dim3(HID * HID / 1024), dim3(256), 0, stream>>>(Waa, W16, abuf, bar);
    k1_xproj<<<dim3((BATCH * SEQ) / 64, HID / 64), dim3(256), 0, stream>>>(X, Wax, ba, out);

    void* args[] = {(void*)&W16, (void*)&out, (void*)&abuf, (void*)&bar};
    hipLaunchCooperativeKernel((void*)k2_scan, dim3(32), dim3(512), args, 0, stream);
}